// Round 2
// baseline (2702.088 us; speedup 1.0000x reference)
//
#include <hip/hip_runtime.h>
#include <cstdint>
#include <cstddef>

#define H 2048
#define F 5504
#define E 8
#define T 2048
#define ROWCAP 6144  // 4096 rows + 8*256 padding worst case

#define BM 256
#define BN 128
#define BK 32

typedef __bf16 bf16x8 __attribute__((ext_vector_type(8)));
typedef float f32x4 __attribute__((ext_vector_type(4)));

#define AS1(p) ((const __attribute__((address_space(1))) void*)(p))
#define AS3(p) ((__attribute__((address_space(3))) void*)(p))

// ---------------- router: fp32 logits, top-2, softmax, slot assignment ----------------
__global__ void router_kernel(const float* __restrict__ x,
                              const float* __restrict__ rw,
                              int* __restrict__ cnt,
                              int* __restrict__ list_t,
                              float* __restrict__ list_w) {
    const int wv = threadIdx.x >> 6;
    const int lane = threadIdx.x & 63;
    const int t = blockIdx.x * 4 + wv;
    const float4* xp = (const float4*)(x + (size_t)t * H) + lane * 8;
    float4 xv[8];
#pragma unroll
    for (int i = 0; i < 8; ++i) xv[i] = xp[i];
    float lg[E];
#pragma unroll
    for (int e = 0; e < E; ++e) {
        const float4* wp = (const float4*)(rw + (size_t)e * H) + lane * 8;
        float acc = 0.f;
#pragma unroll
        for (int i = 0; i < 8; ++i) {
            float4 w4 = wp[i];
            acc += xv[i].x * w4.x + xv[i].y * w4.y + xv[i].z * w4.z + xv[i].w * w4.w;
        }
#pragma unroll
        for (int o = 32; o > 0; o >>= 1) acc += __shfl_xor(acc, o, 64);
        lg[e] = acc;
    }
    if (lane == 0) {
        float v0 = -3e38f, v1 = -3e38f;
        int i0 = 0, i1 = 0;
#pragma unroll
        for (int e = 0; e < E; ++e) {
            float v = lg[e];
            if (v > v0) { v1 = v0; i1 = i0; v0 = v; i0 = e; }
            else if (v > v1) { v1 = v; i1 = e; }
        }
        float p0 = 1.f / (1.f + __expf(v1 - v0));
        float p1 = 1.f - p0;
        int s0 = atomicAdd(&cnt[i0], 1);
        list_t[i0 * T + s0] = t;
        list_w[i0 * T + s0] = p0;
        int s1 = atomicAdd(&cnt[i1], 1);
        list_t[i1 * T + s1] = t;
        list_w[i1 * T + s1] = p1;
    }
}

// ---------------- prefix: 256-aligned per-expert offsets (BM=256 tiles) ----------------
__global__ void offsets_kernel(const int* __restrict__ cnt, int* __restrict__ off) {
    if (threadIdx.x == 0) {
        int acc = 0;
        for (int e = 0; e < E; ++e) {
            off[e] = acc;
            acc += (cnt[e] + 255) & ~255;
        }
    }
}

// ---------------- gather: pack x rows (fp32 -> bf16) per expert ----------------
__global__ void gather_kernel(const float* __restrict__ x,
                              const int* __restrict__ cnt,
                              const int* __restrict__ off,
                              const int* __restrict__ list_t,
                              const float* __restrict__ list_w,
                              __bf16* __restrict__ Abuf,
                              int* __restrict__ row_t,
                              float* __restrict__ row_w) {
    const int e = blockIdx.y, slot = blockIdx.x;
    if (slot >= cnt[e]) return;
    const int row = off[e] + slot;
    if (threadIdx.x == 0) {
        row_t[row] = list_t[e * T + slot];
        row_w[row] = list_w[e * T + slot];
    }
    const int t = list_t[e * T + slot];
    const float4* src = (const float4*)(x + (size_t)t * H);
    float4 a = src[threadIdx.x * 2], b = src[threadIdx.x * 2 + 1];
    bf16x8 o;
    o[0] = (__bf16)a.x; o[1] = (__bf16)a.y; o[2] = (__bf16)a.z; o[3] = (__bf16)a.w;
    o[4] = (__bf16)b.x; o[5] = (__bf16)b.y; o[6] = (__bf16)b.z; o[7] = (__bf16)b.w;
    *(bf16x8*)(Abuf + (size_t)row * H + threadIdx.x * 8) = o;
}

// ---------------- fused gate+up GEMM + SwiGLU epilogue ----------------
// BM=256 x BN=128, BK=32, 512 threads (8 waves: 4 M-bands x 2 N-bands).
// Double-buffered LDS, T3 minimum 2-phase: STAGE(t+1) issued BEFORE compute(t),
// weight regs loaded early / written to LDS after MFMA (T14), ONE barrier/K-step.
// BM=256 halves weight re-reads (avg ~2 M-tiles/expert instead of 4).
__global__ void __launch_bounds__(512, 2)
gateup_kernel(const __bf16* __restrict__ Abuf,
              const float* __restrict__ gw,
              const float* __restrict__ uw,
              const int* __restrict__ cnt,
              const int* __restrict__ off,
              const float* __restrict__ row_w,
              __bf16* __restrict__ act) {
    const int e = blockIdx.z;
    const int count = cnt[e];
    const int mt = blockIdx.x;
    if (mt * BM >= count) return;
    const int n0 = blockIdx.y * BN;
    const int rowbase = off[e] + mt * BM;

    __shared__ __bf16 As[2][BM * BK];  // 16KB x2
    __shared__ __bf16 Gs[2][BN * BK];  // 8KB x2
    __shared__ __bf16 Us[2][BN * BK];  // 8KB x2  => 64KB total

    const int tid = threadIdx.x;
    const int wv = tid >> 6, lane = tid & 63;
    const int wr = wv >> 1, wc = wv & 1;
    const int quad = lane >> 4, l16 = lane & 15;

    f32x4 accG[4][4] = {};
    f32x4 accU[4][4] = {};

    const __bf16* abase = Abuf + (size_t)rowbase * H;
    const float* gbase = gw + (size_t)e * F * H + (size_t)n0 * H;
    const float* ubase = uw + (size_t)e * F * H + (size_t)n0 * H;

    const int arow = lane >> 2;       // row within 16-row segment
    const int acol = (lane & 3) * 8;  // k-element offset (16B chunks)
    const int wrow = tid >> 2;        // 0..127 weight row
    const int wk = (tid & 3) * 8;     // k-element offset (32B fp32 chunks)

    float4 pg0, pg1, pu0, pu1;  // prefetched fp32 weight regs

#define STAGE_A(buf, k0)                                                                     \
    do {                                                                                     \
        _Pragma("unroll")                                                                    \
        for (int i_ = 0; i_ < 2; ++i_) {                                                     \
            const int seg_ = i_ * 8 + wv;                                                    \
            const __bf16* gp_ = abase + (size_t)(seg_ * 16 + arow) * H + (k0) + acol;        \
            __builtin_amdgcn_global_load_lds(AS1(gp_), AS3(&As[buf][seg_ * 512]), 16, 0, 0); \
        }                                                                                    \
    } while (0)

#define LOAD_W(k0)                                                                   \
    do {                                                                             \
        const float4* gp_ = (const float4*)(gbase + (size_t)wrow * H + (k0) + wk);   \
        pg0 = gp_[0]; pg1 = gp_[1];                                                  \
        const float4* up_ = (const float4*)(ubase + (size_t)wrow * H + (k0) + wk);   \
        pu0 = up_[0]; pu1 = up_[1];                                                  \
    } while (0)

#define WRITE_W(buf)                                                                             \
    do {                                                                                         \
        bf16x8 hg_, hu_;                                                                         \
        hg_[0] = (__bf16)pg0.x; hg_[1] = (__bf16)pg0.y; hg_[2] = (__bf16)pg0.z; hg_[3] = (__bf16)pg0.w; \
        hg_[4] = (__bf16)pg1.x; hg_[5] = (__bf16)pg1.y; hg_[6] = (__bf16)pg1.z; hg_[7] = (__bf16)pg1.w; \
        hu_[0] = (__bf16)pu0.x; hu_[1] = (__bf16)pu0.y; hu_[2] = (__bf16)pu0.z; hu_[3] = (__bf16)pu0.w; \
        hu_[4] = (__bf16)pu1.x; hu_[5] = (__bf16)pu1.y; hu_[6] = (__bf16)pu1.z; hu_[7] = (__bf16)pu1.w; \
        *(bf16x8*)(&Gs[buf][wrow * BK + wk]) = hg_;                                              \
        *(bf16x8*)(&Us[buf][wrow * BK + wk]) = hu_;                                              \
    } while (0)

#define COMPUTE(buf)                                                                             \
    do {                                                                                         \
        bf16x8 af_[4], gf_[4], uf_[4];                                                           \
        _Pragma("unroll")                                                                        \
        for (int i_ = 0; i_ < 4; ++i_)                                                           \
            af_[i_] = *(const bf16x8*)(&As[buf][(wr * 64 + i_ * 16 + l16) * BK + quad * 8]);     \
        _Pragma("unroll")                                                                        \
        for (int j_ = 0; j_ < 4; ++j_) {                                                         \
            gf_[j_] = *(const bf16x8*)(&Gs[buf][(wc * 64 + j_ * 16 + l16) * BK + quad * 8]);     \
            uf_[j_] = *(const bf16x8*)(&Us[buf][(wc * 64 + j_ * 16 + l16) * BK + quad * 8]);     \
        }                                                                                        \
        _Pragma("unroll")                                                                        \
        for (int i_ = 0; i_ < 4; ++i_)                                                           \
            _Pragma("unroll")                                                                    \
            for (int j_ = 0; j_ < 4; ++j_) {                                                     \
                accG[i_][j_] = __builtin_amdgcn_mfma_f32_16x16x32_bf16(af_[i_], gf_[j_], accG[i_][j_], 0, 0, 0); \
                accU[i_][j_] = __builtin_amdgcn_mfma_f32_16x16x32_bf16(af_[i_], uf_[j_], accU[i_][j_], 0, 0, 0); \
            }                                                                                    \
    } while (0)

    // prologue: fill buffer 0
    STAGE_A(0, 0);
    LOAD_W(0);
    WRITE_W(0);
    __syncthreads();  // drains vmcnt (A stage) + lgkmcnt (W writes)

    const int NT = H / BK;  // 64
    for (int t = 0; t < NT - 1; ++t) {
        const int cur = t & 1, nxt = cur ^ 1;
        const int k1 = (t + 1) * BK;
        STAGE_A(nxt, k1);   // async global->LDS, in flight across compute
        LOAD_W(k1);         // fp32 weight loads -> regs, latency hidden by MFMA
        COMPUTE(cur);
        WRITE_W(nxt);       // convert + LDS write after compute
        __syncthreads();    // one barrier per K-step
    }
    COMPUTE((NT - 1) & 1);

#undef STAGE_A
#undef LOAD_W
#undef WRITE_W
#undef COMPUTE

    // epilogue: act = silu(g) * u * combine_w
#pragma unroll
    for (int i = 0; i < 4; ++i) {
        const int ml = wr * 64 + i * 16 + quad * 4;
#pragma unroll
        for (int r = 0; r < 4; ++r) {
            const float w = row_w[rowbase + ml + r];
            __bf16* arow_p = act + (size_t)(rowbase + ml + r) * F + n0;
#pragma unroll
            for (int j = 0; j < 4; ++j) {
                const int nl = wc * 64 + j * 16 + l16;
                float g = accG[i][j][r], u = accU[i][j][r];
                float s = g / (1.f + __expf(-g));
                arow_p[nl] = (__bf16)(s * u * w);
            }
        }
    }
}

// ---------------- down GEMM + scatter-add ----------------
// Same BM=256/BN=128/BK=32 double-buffered 2-phase structure.
__global__ void __launch_bounds__(512, 2)
down_kernel(const __bf16* __restrict__ act,
            const float* __restrict__ dw,
            const int* __restrict__ cnt,
            const int* __restrict__ off,
            const int* __restrict__ row_t,
            float* __restrict__ out) {
    const int e = blockIdx.z;
    const int count = cnt[e];
    const int mt = blockIdx.x;
    if (mt * BM >= count) return;
    const int h0 = blockIdx.y * BN;
    const int rowbase = off[e] + mt * BM;

    __shared__ __bf16 As[2][BM * BK];  // 16KB x2
    __shared__ __bf16 Ws[2][BN * BK];  // 8KB x2

    const int tid = threadIdx.x;
    const int wv = tid >> 6, lane = tid & 63;
    const int wr = wv >> 1, wc = wv & 1;
    const int quad = lane >> 4, l16 = lane & 15;

    f32x4 acc[4][4] = {};

    const __bf16* abase = act + (size_t)rowbase * F;
    const float* wbase = dw + (size_t)e * H * F + (size_t)h0 * F;

    const int arow = lane >> 2;
    const int acol = (lane & 3) * 8;
    const int wrow = tid >> 2;
    const int wk = (tid & 3) * 8;

    float4 pw0, pw1;

#define STAGE_A(buf, k0)                                                                     \
    do {                                                                                     \
        _Pragma("unroll")                                                                    \
        for (int i_ = 0; i_ < 2; ++i_) {                                                     \
            const int seg_ = i_ * 8 + wv;                                                    \
            const __bf16* gp_ = abase + (size_t)(seg_ * 16 + arow) * F + (k0) + acol;        \
            __builtin_amdgcn_global_load_lds(AS1(gp_), AS3(&As[buf][seg_ * 512]), 16, 0, 0); \
        }                                                                                    \
    } while (0)

#define LOAD_W(k0)                                                                   \
    do {                                                                             \
        const float4* gp_ = (const float4*)(wbase + (size_t)wrow * F + (k0) + wk);   \
        pw0 = gp_[0]; pw1 = gp_[1];                                                  \
    } while (0)

#define WRITE_W(buf)                                                                             \
    do {                                                                                         \
        bf16x8 hw_;                                                                              \
        hw_[0] = (__bf16)pw0.x; hw_[1] = (__bf16)pw0.y; hw_[2] = (__bf16)pw0.z; hw_[3] = (__bf16)pw0.w; \
        hw_[4] = (__bf16)pw1.x; hw_[5] = (__bf16)pw1.y; hw_[6] = (__bf16)pw1.z; hw_[7] = (__bf16)pw1.w; \
        *(bf16x8*)(&Ws[buf][wrow * BK + wk]) = hw_;                                              \
    } while (0)

#define COMPUTE(buf)                                                                             \
    do {                                                                                         \
        bf16x8 af_[4], bf_[4];                                                                   \
        _Pragma("unroll")                                                                        \
        for (int i_ = 0; i_ < 4; ++i_)                                                           \
            af_[i_] = *(const bf16x8*)(&As[buf][(wr * 64 + i_ * 16 + l16) * BK + quad * 8]);     \
        _Pragma("unroll")                                                                        \
        for (int j_ = 0; j_ < 4; ++j_)                                                           \
            bf_[j_] = *(const bf16x8*)(&Ws[buf][(wc * 64 + j_ * 16 + l16) * BK + quad * 8]);     \
        _Pragma("unroll")                                                                        \
        for (int i_ = 0; i_ < 4; ++i_)                                                           \
            _Pragma("unroll")                                                                    \
            for (int j_ = 0; j_ < 4; ++j_)                                                       \
                acc[i_][j_] = __builtin_amdgcn_mfma_f32_16x16x32_bf16(af_[i_], bf_[j_], acc[i_][j_], 0, 0, 0); \
    } while (0)

    STAGE_A(0, 0);
    LOAD_W(0);
    WRITE_W(0);
    __syncthreads();

    const int NT = F / BK;  // 172
    for (int t = 0; t < NT - 1; ++t) {
        const int cur = t & 1, nxt = cur ^ 1;
        const int k1 = (t + 1) * BK;
        STAGE_A(nxt, k1);
        LOAD_W(k1);
        COMPUTE(cur);
        WRITE_W(nxt);
        __syncthreads();
    }
    COMPUTE((NT - 1) & 1);

#undef STAGE_A
#undef LOAD_W
#undef WRITE_W
#undef COMPUTE

#pragma unroll
    for (int i = 0; i < 4; ++i) {
        const int ml = wr * 64 + i * 16 + quad * 4;
#pragma unroll
        for (int r = 0; r < 4; ++r) {
            const int lr = mt * BM + ml + r;
            if (lr < count) {
                const int t = row_t[rowbase + ml + r];
                float* orow = out + (size_t)t * H + h0;
#pragma unroll
                for (int j = 0; j < 4; ++j)
                    atomicAdd(&orow[wc * 64 + j * 16 + l16], acc[i][j][r]);
            }
        }
    }
}

extern "C" void kernel_launch(void* const* d_in, const int* in_sizes, int n_in,
                              void* d_out, int out_size, void* d_ws, size_t ws_size,
                              hipStream_t stream) {
    const float* x  = (const float*)d_in[0];
    const float* rw = (const float*)d_in[1];
    const float* gw = (const float*)d_in[2];
    const float* uw = (const float*)d_in[3];
    const float* dw = (const float*)d_in[4];
    float* out = (float*)d_out;
    char* ws = (char*)d_ws;

    int*   cnt    = (int*)(ws + 0);
    int*   off    = (int*)(ws + 256);
    int*   list_t = (int*)(ws + 1024);
    float* list_w = (float*)(ws + 1024 + 65536);
    int*   row_t  = (int*)(ws + 1024 + 2 * 65536);
    float* row_w  = (float*)(ws + 1024 + 2 * 65536 + ROWCAP * 4);
    __bf16* Abuf  = (__bf16*)(ws + 262144);
    __bf16* act   = (__bf16*)(ws + 262144 + (size_t)ROWCAP * H * 2);

    hipMemsetAsync(d_out, 0, (size_t)out_size * sizeof(float), stream);
    hipMemsetAsync(ws, 0, 1024, stream);

    router_kernel<<<T / 4, 256, 0, stream>>>(x, rw, cnt, list_t, list_w);
    offsets_kernel<<<1, 64, 0, stream>>>(cnt, off);
    gather_kernel<<<dim3(T, E), 256, 0, stream>>>(x, cnt, off, list_t, list_w, Abuf, row_t, row_w);
    gateup_kernel<<<dim3(8, F / BN, E), 512, 0, stream>>>(Abuf, gw, uw, cnt, off, row_w, act);
    down_kernel<<<dim3(8, H / BN, E), 512, 0, stream>>>(act, dw, cnt, off, row_t, out);
}

// Round 4
// 1663.912 us; speedup vs baseline: 1.6239x; 1.6239x over previous
//
#include <hip/hip_runtime.h>
#include <cstdint>
#include <cstddef>

#define H 2048
#define F 5504
#define E 8
#define T 2048
#define ROWCAP 5120  // 4096 rows + 8*128 padding worst case

#define BM 128
#define BN 128
#define BK 32

typedef __bf16 bf16x8 __attribute__((ext_vector_type(8)));
typedef float f32x4 __attribute__((ext_vector_type(4)));

#define AS1(p) ((const __attribute__((address_space(1))) void*)(p))
#define AS3(p) ((__attribute__((address_space(3))) void*)(p))

// ---------------- router: fp32 logits, top-2, softmax, slot assignment ----------------
__global__ void router_kernel(const float* __restrict__ x,
                              const float* __restrict__ rw,
                              int* __restrict__ cnt,
                              int* __restrict__ list_t,
                              float* __restrict__ list_w) {
    const int wv = threadIdx.x >> 6;
    const int lane = threadIdx.x & 63;
    const int t = blockIdx.x * 4 + wv;
    const float4* xp = (const float4*)(x + (size_t)t * H) + lane * 8;
    float4 xv[8];
#pragma unroll
    for (int i = 0; i < 8; ++i) xv[i] = xp[i];
    float lg[E];
#pragma unroll
    for (int e = 0; e < E; ++e) {
        const float4* wp = (const float4*)(rw + (size_t)e * H) + lane * 8;
        float acc = 0.f;
#pragma unroll
        for (int i = 0; i < 8; ++i) {
            float4 w4 = wp[i];
            acc += xv[i].x * w4.x + xv[i].y * w4.y + xv[i].z * w4.z + xv[i].w * w4.w;
        }
#pragma unroll
        for (int o = 32; o > 0; o >>= 1) acc += __shfl_xor(acc, o, 64);
        lg[e] = acc;
    }
    if (lane == 0) {
        float v0 = -3e38f, v1 = -3e38f;
        int i0 = 0, i1 = 0;
#pragma unroll
        for (int e = 0; e < E; ++e) {
            float v = lg[e];
            if (v > v0) { v1 = v0; i1 = i0; v0 = v; i0 = e; }
            else if (v > v1) { v1 = v; i1 = e; }
        }
        float p0 = 1.f / (1.f + __expf(v1 - v0));
        float p1 = 1.f - p0;
        int s0 = atomicAdd(&cnt[i0], 1);
        list_t[i0 * T + s0] = t;
        list_w[i0 * T + s0] = p0;
        int s1 = atomicAdd(&cnt[i1], 1);
        list_t[i1 * T + s1] = t;
        list_w[i1 * T + s1] = p1;
    }
}

// ---------------- prefix: 128-aligned per-expert offsets ----------------
__global__ void offsets_kernel(const int* __restrict__ cnt, int* __restrict__ off) {
    if (threadIdx.x == 0) {
        int acc = 0;
        for (int e = 0; e < E; ++e) {
            off[e] = acc;
            acc += (cnt[e] + 127) & ~127;
        }
    }
}

// ---------------- gather: pack x rows (fp32 -> bf16) per expert ----------------
__global__ void gather_kernel(const float* __restrict__ x,
                              const int* __restrict__ cnt,
                              const int* __restrict__ off,
                              const int* __restrict__ list_t,
                              const float* __restrict__ list_w,
                              __bf16* __restrict__ Abuf,
                              int* __restrict__ row_t,
                              float* __restrict__ row_w) {
    const int e = blockIdx.y, slot = blockIdx.x;
    if (slot >= cnt[e]) return;
    const int row = off[e] + slot;
    if (threadIdx.x == 0) {
        row_t[row] = list_t[e * T + slot];
        row_w[row] = list_w[e * T + slot];
    }
    const int t = list_t[e * T + slot];
    const float4* src = (const float4*)(x + (size_t)t * H);
    float4 a = src[threadIdx.x * 2], b = src[threadIdx.x * 2 + 1];
    bf16x8 o;
    o[0] = (__bf16)a.x; o[1] = (__bf16)a.y; o[2] = (__bf16)a.z; o[3] = (__bf16)a.w;
    o[4] = (__bf16)b.x; o[5] = (__bf16)b.y; o[6] = (__bf16)b.z; o[7] = (__bf16)b.w;
    *(bf16x8*)(Abuf + (size_t)row * H + threadIdx.x * 8) = o;
}

// ---------------- fused gate+up GEMM + SwiGLU epilogue ----------------
// Round-1 shape (BM=128, 256 thr, 4 waves => ~236 regs/wave => 2 waves/SIMD
// => 2 blocks/CU, cross-block overlap preserved) + 2-phase pipeline:
//   STAGE(t+1) + LOAD_W(t+1) issued BEFORE COMPUTE(t); cvt+ds_write after;
//   ONE barrier per K-step. Statically-named dual LDS buffers (As0/As1,...)
//   so the compiler can disambiguate ds_read(cur) from global_load_lds(nxt).
// Grid x = N-tile (43) so active blocks round-robin across all 8 XCDs
// (round-2 lesson: x = M-tile put all work on XCDs 0-3).
__global__ void __launch_bounds__(256, 2)
gateup_kernel(const __bf16* __restrict__ Abuf,
              const float* __restrict__ gw,
              const float* __restrict__ uw,
              const int* __restrict__ cnt,
              const int* __restrict__ off,
              const float* __restrict__ row_w,
              __bf16* __restrict__ act) {
    const int e = blockIdx.z;
    const int count = cnt[e];
    const int mt = blockIdx.y;
    if (mt * BM >= count) return;
    const int n0 = blockIdx.x * BN;
    const int rowbase = off[e] + mt * BM;

    __shared__ __bf16 As0[BM * BK], As1[BM * BK];  // 8KB each
    __shared__ __bf16 Gs0[BN * BK], Gs1[BN * BK];
    __shared__ __bf16 Us0[BN * BK], Us1[BN * BK];  // total 48KB

    const int tid = threadIdx.x;
    const int wv = tid >> 6, lane = tid & 63;
    const int wr = wv >> 1, wc = wv & 1;
    const int quad = lane >> 4, l16 = lane & 15;

    f32x4 accG[4][4] = {};
    f32x4 accU[4][4] = {};

    const __bf16* abase = Abuf + (size_t)rowbase * H;
    const float* gbase = gw + (size_t)e * F * H + (size_t)n0 * H;
    const float* ubase = uw + (size_t)e * F * H + (size_t)n0 * H;

    const int arow = lane >> 2;       // row within 16-row segment
    const int acol = (lane & 3) * 8;  // k-element offset (16B chunks)
    const int wrow = tid >> 1;        // 0..127 weight row
    const int kh = (tid & 1) * 16;    // k-float offset (64B halves)

    float4 pg[4], pu[4];  // prefetched fp32 weight regs (held across COMPUTE)

#define STAGE_A(AS, k0)                                                                  \
    do {                                                                                 \
        _Pragma("unroll")                                                                \
        for (int i_ = 0; i_ < 2; ++i_) {                                                 \
            const int seg_ = wv * 2 + i_;                                                \
            const __bf16* gp_ = abase + (size_t)(seg_ * 16 + arow) * H + (k0) + acol;    \
            __builtin_amdgcn_global_load_lds(AS1(gp_), AS3(AS + seg_ * 512), 16, 0, 0);  \
        }                                                                                \
    } while (0)

#define LOAD_W(k0)                                                                   \
    do {                                                                             \
        const float4* gp_ = (const float4*)(gbase + (size_t)wrow * H + (k0) + kh);   \
        pg[0] = gp_[0]; pg[1] = gp_[1]; pg[2] = gp_[2]; pg[3] = gp_[3];              \
        const float4* up_ = (const float4*)(ubase + (size_t)wrow * H + (k0) + kh);   \
        pu[0] = up_[0]; pu[1] = up_[1]; pu[2] = up_[2]; pu[3] = up_[3];              \
    } while (0)

#define WRITE_W(GS, US)                                                                          \
    do {                                                                                         \
        bf16x8 h0_, h1_;                                                                         \
        h0_[0] = (__bf16)pg[0].x; h0_[1] = (__bf16)pg[0].y; h0_[2] = (__bf16)pg[0].z; h0_[3] = (__bf16)pg[0].w; \
        h0_[4] = (__bf16)pg[1].x; h0_[5] = (__bf16)pg[1].y; h0_[6] = (__bf16)pg[1].z; h0_[7] = (__bf16)pg[1].w; \
        h1_[0] = (__bf16)pg[2].x; h1_[1] = (__bf16)pg[2].y; h1_[2] = (__bf16)pg[2].z; h1_[3] = (__bf16)pg[2].w; \
        h1_[4] = (__bf16)pg[3].x; h1_[5] = (__bf16)pg[3].y; h1_[6] = (__bf16)pg[3].z; h1_[7] = (__bf16)pg[3].w; \
        *(bf16x8*)(GS + wrow * BK + kh) = h0_;                                                   \
        *(bf16x8*)(GS + wrow * BK + kh + 8) = h1_;                                               \
        h0_[0] = (__bf16)pu[0].x; h0_[1] = (__bf16)pu[0].y; h0_[2] = (__bf16)pu[0].z; h0_[3] = (__bf16)pu[0].w; \
        h0_[4] = (__bf16)pu[1].x; h0_[5] = (__bf16)pu[1].y; h0_[6] = (__bf16)pu[1].z; h0_[7] = (__bf16)pu[1].w; \
        h1_[0] = (__bf16)pu[2].x; h1_[1] = (__bf16)pu[2].y; h1_[2] = (__bf16)pu[2].z; h1_[3] = (__bf16)pu[2].w; \
        h1_[4] = (__bf16)pu[3].x; h1_[5] = (__bf16)pu[3].y; h1_[6] = (__bf16)pu[3].z; h1_[7] = (__bf16)pu[3].w; \
        *(bf16x8*)(US + wrow * BK + kh) = h0_;                                                   \
        *(bf16x8*)(US + wrow * BK + kh + 8) = h1_;                                               \
    } while (0)

#define COMPUTE(AS, GS, US)                                                                      \
    do {                                                                                         \
        bf16x8 af_[4], gf_[4], uf_[4];                                                           \
        _Pragma("unroll")                                                                        \
        for (int i_ = 0; i_ < 4; ++i_)                                                           \
            af_[i_] = *(const bf16x8*)(AS + (wr * 64 + i_ * 16 + l16) * BK + quad * 8);          \
        _Pragma("unroll")                                                                        \
        for (int j_ = 0; j_ < 4; ++j_) {                                                         \
            gf_[j_] = *(const bf16x8*)(GS + (wc * 64 + j_ * 16 + l16) * BK + quad * 8);          \
            uf_[j_] = *(const bf16x8*)(US + (wc * 64 + j_ * 16 + l16) * BK + quad * 8);          \
        }                                                                                        \
        _Pragma("unroll")                                                                        \
        for (int i_ = 0; i_ < 4; ++i_)                                                           \
            _Pragma("unroll")                                                                    \
            for (int j_ = 0; j_ < 4; ++j_) {                                                     \
                accG[i_][j_] = __builtin_amdgcn_mfma_f32_16x16x32_bf16(af_[i_], gf_[j_], accG[i_][j_], 0, 0, 0); \
                accU[i_][j_] = __builtin_amdgcn_mfma_f32_16x16x32_bf16(af_[i_], uf_[j_], accU[i_][j_], 0, 0, 0); \
            }                                                                                    \
    } while (0)

    // prologue: fill buffer 0
    STAGE_A(As0, 0);
    LOAD_W(0);
    WRITE_W(Gs0, Us0);
    __syncthreads();

    const int NT = H / BK;  // 64 (even)
    for (int t = 0; t < NT; t += 2) {
        // phase 1: compute buf0, stage buf1 for step t+1
        STAGE_A(As1, (t + 1) * BK);
        LOAD_W((t + 1) * BK);
        COMPUTE(As0, Gs0, Us0);
        WRITE_W(Gs1, Us1);
        __syncthreads();
        // phase 2: compute buf1, stage buf0 for step t+2
        if (t + 2 < NT) {
            STAGE_A(As0, (t + 2) * BK);
            LOAD_W((t + 2) * BK);
        }
        COMPUTE(As1, Gs1, Us1);
        if (t + 2 < NT) WRITE_W(Gs0, Us0);
        __syncthreads();
    }

#undef STAGE_A
#undef LOAD_W
#undef WRITE_W
#undef COMPUTE

    // epilogue: act = silu(g) * u * combine_w
#pragma unroll
    for (int i = 0; i < 4; ++i) {
        const int ml = wr * 64 + i * 16 + quad * 4;
#pragma unroll
        for (int r = 0; r < 4; ++r) {
            const float w = row_w[rowbase + ml + r];
            __bf16* arow_p = act + (size_t)(rowbase + ml + r) * F + n0;
#pragma unroll
            for (int j = 0; j < 4; ++j) {
                const int nl = wc * 64 + j * 16 + l16;
                float g = accG[i][j][r], u = accU[i][j][r];
                float s = g / (1.f + __expf(-g));
                arow_p[nl] = (__bf16)(s * u * w);
            }
        }
    }
}

// ---------------- down GEMM + scatter-add ----------------
// Same 2-phase double-buffered structure, single accumulator set.
__global__ void __launch_bounds__(256, 2)
down_kernel(const __bf16* __restrict__ act,
            const float* __restrict__ dw,
            const int* __restrict__ cnt,
            const int* __restrict__ off,
            const int* __restrict__ row_t,
              float* __restrict__ out) {
    const int e = blockIdx.z;
    const int count = cnt[e];
    const int mt = blockIdx.y;
    if (mt * BM >= count) return;
    const int h0 = blockIdx.x * BN;
    const int rowbase = off[e] + mt * BM;

    __shared__ __bf16 As0[BM * BK], As1[BM * BK];
    __shared__ __bf16 Ws0[BN * BK], Ws1[BN * BK];  // 32KB total

    const int tid = threadIdx.x;
    const int wv = tid >> 6, lane = tid & 63;
    const int wr = wv >> 1, wc = wv & 1;
    const int quad = lane >> 4, l16 = lane & 15;

    f32x4 acc[4][4] = {};

    const __bf16* abase = act + (size_t)rowbase * F;
    const float* wbase = dw + (size_t)e * H * F + (size_t)h0 * F;

    const int arow = lane >> 2;
    const int acol = (lane & 3) * 8;
    const int wrow = tid >> 1;
    const int kh = (tid & 1) * 16;

    float4 pw[4];

#define STAGE_A(AS, k0)                                                                  \
    do {                                                                                 \
        _Pragma("unroll")                                                                \
        for (int i_ = 0; i_ < 2; ++i_) {                                                 \
            const int seg_ = wv * 2 + i_;                                                \
            const __bf16* gp_ = abase + (size_t)(seg_ * 16 + arow) * F + (k0) + acol;    \
            __builtin_amdgcn_global_load_lds(AS1(gp_), AS3(AS + seg_ * 512), 16, 0, 0);  \
        }                                                                                \
    } while (0)

#define LOAD_W(k0)                                                                   \
    do {                                                                             \
        const float4* gp_ = (const float4*)(wbase + (size_t)wrow * F + (k0) + kh);   \
        pw[0] = gp_[0]; pw[1] = gp_[1]; pw[2] = gp_[2]; pw[3] = gp_[3];              \
    } while (0)

#define WRITE_W(WS)                                                                              \
    do {                                                                                         \
        bf16x8 h0_, h1_;                                                                         \
        h0_[0] = (__bf16)pw[0].x; h0_[1] = (__bf16)pw[0].y; h0_[2] = (__bf16)pw[0].z; h0_[3] = (__bf16)pw[0].w; \
        h0_[4] = (__bf16)pw[1].x; h0_[5] = (__bf16)pw[1].y; h0_[6] = (__bf16)pw[1].z; h0_[7] = (__bf16)pw[1].w; \
        h1_[0] = (__bf16)pw[2].x; h1_[1] = (__bf16)pw[2].y; h1_[2] = (__bf16)pw[2].z; h1_[3] = (__bf16)pw[2].w; \
        h1_[4] = (__bf16)pw[3].x; h1_[5] = (__bf16)pw[3].y; h1_[6] = (__bf16)pw[3].z; h1_[7] = (__bf16)pw[3].w; \
        *(bf16x8*)(WS + wrow * BK + kh) = h0_;                                                   \
        *(bf16x8*)(WS + wrow * BK + kh + 8) = h1_;                                               \
    } while (0)

#define COMPUTE(AS, WS)                                                                          \
    do {                                                                                         \
        bf16x8 af_[4], bf_[4];                                                                   \
        _Pragma("unroll")                                                                        \
        for (int i_ = 0; i_ < 4; ++i_)                                                           \
            af_[i_] = *(const bf16x8*)(AS + (wr * 64 + i_ * 16 + l16) * BK + quad * 8);          \
        _Pragma("unroll")                                                                        \
        for (int j_ = 0; j_ < 4; ++j_)                                                           \
            bf_[j_] = *(const bf16x8*)(WS + (wc * 64 + j_ * 16 + l16) * BK + quad * 8);          \
        _Pragma("unroll")                                                                        \
        for (int i_ = 0; i_ < 4; ++i_)                                                           \
            _Pragma("unroll")                                                                    \
            for (int j_ = 0; j_ < 4; ++j_)                                                       \
                acc[i_][j_] = __builtin_amdgcn_mfma_f32_16x16x32_bf16(af_[i_], bf_[j_], acc[i_][j_], 0, 0, 0); \
    } while (0)

    STAGE_A(As0, 0);
    LOAD_W(0);
    WRITE_W(Ws0);
    __syncthreads();

    const int NT = F / BK;  // 172 (even)
    for (int t = 0; t < NT; t += 2) {
        STAGE_A(As1, (t + 1) * BK);
        LOAD_W((t + 1) * BK);
        COMPUTE(As0, Ws0);
        WRITE_W(Ws1);
        __syncthreads();
        if (t + 2 < NT) {
            STAGE_A(As0, (t + 2) * BK);
            LOAD_W((t + 2) * BK);
        }
        COMPUTE(As1, Ws1);
        if (t + 2 < NT) WRITE_W(Ws0);
        __syncthreads();
    }

#undef STAGE_A
#undef LOAD_W
#undef WRITE_W
#undef COMPUTE

#pragma unroll
    for (int i = 0; i < 4; ++i) {
        const int ml = wr * 64 + i * 16 + quad * 4;
#pragma unroll
        for (int r = 0; r < 4; ++r) {
            const int lr = mt * BM + ml + r;
            if (lr < count) {
                const int t = row_t[rowbase + ml + r];
                float* orow = out + (size_t)t * H + h0;
#pragma unroll
                for (int j = 0; j < 4; ++j)
                    atomicAdd(&orow[wc * 64 + j * 16 + l16], acc[i][j][r]);
            }
        }
    }
}

extern "C" void kernel_launch(void* const* d_in, const int* in_sizes, int n_in,
                              void* d_out, int out_size, void* d_ws, size_t ws_size,
                              hipStream_t stream) {
    const float* x  = (const float*)d_in[0];
    const float* rw = (const float*)d_in[1];
    const float* gw = (const float*)d_in[2];
    const float* uw = (const float*)d_in[3];
    const float* dw = (const float*)d_in[4];
    float* out = (float*)d_out;
    char* ws = (char*)d_ws;

    int*   cnt    = (int*)(ws + 0);
    int*   off    = (int*)(ws + 256);
    int*   list_t = (int*)(ws + 1024);
    float* list_w = (float*)(ws + 1024 + 65536);
    int*   row_t  = (int*)(ws + 1024 + 2 * 65536);
    float* row_w  = (float*)(ws + 1024 + 2 * 65536 + ROWCAP * 4);
    __bf16* Abuf  = (__bf16*)(ws + 262144);
    __bf16* act   = (__bf16*)(ws + 262144 + (size_t)ROWCAP * H * 2);

    hipMemsetAsync(d_out, 0, (size_t)out_size * sizeof(float), stream);
    hipMemsetAsync(ws, 0, 1024, stream);

    router_kernel<<<T / 4, 256, 0, stream>>>(x, rw, cnt, list_t, list_w);
    offsets_kernel<<<1, 64, 0, stream>>>(cnt, off);
    gather_kernel<<<dim3(T, E), 256, 0, stream>>>(x, cnt, off, list_t, list_w, Abuf, row_t, row_w);
    gateup_kernel<<<dim3(F / BN, T / BM, E), 256, 0, stream>>>(Abuf, gw, uw, cnt, off, row_w, act);
    down_kernel<<<dim3(H / BN, T / BM, E), 256, 0, stream>>>(act, dw, cnt, off, row_t, out);
}